// Round 3
// baseline (1005.683 us; speedup 1.0000x reference)
//
#include <hip/hip_runtime.h>
#include <cstdint>
#include <cstddef>

// Problem constants (match reference setup_inputs)
#define BB 32
#define SS 4096          // 2^12
#define FEAT_ 64
#define HID_ 32
#define NN 1024          // MAX_NODES
#define RPB 16           // adjacency rows per block
#define MAXL 1024        // LDS edge-list capacity (expected ~128/block)

// ---------------------------------------------------------------------------
// Kernel 1: node_features via GATHER (no atomics) + fused L2-normalize.
// One block = 256 threads = 4 waves = 4 node rows of one batch.
// Block stages dst[b, 0..S) in LDS (16 KB); each wave scans it in 64
// ballot-iterations. Row sum accumulated in-register (deterministic s-order),
// L2-normalized via 64-lane butterfly, written out directly.
// ---------------------------------------------------------------------------
__global__ void node_feat_kernel(const float* __restrict__ flow,
                                 const int* __restrict__ dst,
                                 float* __restrict__ nf) {
    int row0 = blockIdx.x << 2;              // global row = b*NN + node
    int b = row0 >> 10;
    __shared__ int sdst[SS];

    const int4* g = (const int4*)(dst + (size_t)b * SS);
    int4* sd4 = (int4*)sdst;
    for (int i = threadIdx.x; i < SS / 4; i += 256) sd4[i] = g[i];
    __syncthreads();

    int wave = threadIdx.x >> 6;
    int lane = threadIdx.x & 63;
    int node = (row0 + wave) & (NN - 1);
    const float* fb = flow + ((size_t)b * SS << 6);

    float acc = 0.0f;
    for (int s0 = 0; s0 < SS; s0 += 64) {
        int d = sdst[s0 + lane];
        unsigned long long m = __ballot(d == node);
        while (m) {
            int bit = __ffsll((long long)m) - 1;
            m &= m - 1;
            acc += fb[((s0 + bit) << 6) + lane];   // coalesced 256 B row read
        }
    }

    float ss = acc * acc;
    #pragma unroll
    for (int off = 32; off > 0; off >>= 1) ss += __shfl_xor(ss, off, 64);
    float denom = fmaxf(sqrtf(ss), 1e-12f);
    nf[((size_t)(row0 + wave) << 6) + lane] = acc / denom;
}

// ---------------------------------------------------------------------------
// Kernel 2: edge MLP -> weight w[b,s] into workspace. No adjacency access.
// ---------------------------------------------------------------------------
__global__ void mlp_kernel(const int* __restrict__ src,
                           const int* __restrict__ dst,
                           const float* __restrict__ vol,
                           const float* __restrict__ emb,
                           const float* __restrict__ W1,
                           const float* __restrict__ b1,
                           const float* __restrict__ W2,
                           const float* __restrict__ b2,
                           float* __restrict__ wout) {
    int i = blockIdx.x * blockDim.x + threadIdx.x;  // b*S + s
    int si = src[i], di = dst[i];

    float acc[HID_];
    #pragma unroll
    for (int j = 0; j < HID_; ++j) acc[j] = b1[j];

    // h = relu([emb[src]; emb[dst]] @ W1 + b1). W1 accesses are wave-uniform
    // (scalar-load friendly); emb rows are gathered, 256 B each, L2-resident.
    #pragma unroll
    for (int half = 0; half < 2; ++half) {
        const float* e = emb + ((half ? di : si) << 6);
        const float* w = W1 + half * 64 * HID_;
        for (int k = 0; k < 64; k += 4) {
            float4 v = *(const float4*)(e + k);
            #pragma unroll
            for (int j = 0; j < HID_; ++j) {
                float a = acc[j];
                a += v.x * w[(k + 0) * HID_ + j];
                a += v.y * w[(k + 1) * HID_ + j];
                a += v.z * w[(k + 2) * HID_ + j];
                a += v.w * w[(k + 3) * HID_ + j];
                acc[j] = a;
            }
        }
    }

    float dotv = b2[0];
    #pragma unroll
    for (int j = 0; j < HID_; ++j) dotv += fmaxf(acc[j], 0.0f) * W2[j];
    float edge_w = 1.0f / (1.0f + expf(-dotv));
    float vol_w  = 1.0f / (1.0f + expf(-vol[i] / 1000.0f));
    wout[i] = edge_w * vol_w;
}

// ---------------------------------------------------------------------------
// Kernel 3: adjacency writer — each byte written exactly once, no memset,
// no global atomics. Block owns RPB=16 rows of one batch.
//   prio = s+1      for pass-1 cell (src,dst)
//   prio = S+s+1    for pass-2 cell (dst,src)
// max prio per cell == numpy last-write-wins (pass 2 overwrites pass 1).
// Matched edges (~128/block) go into an LDS list + per-row bitmaps; the
// streaming phase emits zeros except at bitmap hits (max-prio w from list).
// ---------------------------------------------------------------------------
__global__ void adj_row_kernel(const int* __restrict__ src,
                               const int* __restrict__ dst,
                               const float* __restrict__ wbuf,
                               float* __restrict__ adj) {
    int b  = blockIdx.x >> 6;                 // 64 blocks per batch
    int r0 = (blockIdx.x & 63) << 4;          // first of RPB rows
    int tid = threadIdx.x;

    __shared__ int ssrc[SS];
    __shared__ int sdst[SS];
    __shared__ unsigned sbits[RPB][NN / 32];  // 2 KB bitmaps
    __shared__ int lrc[MAXL];                 // (localRow<<16) | col
    __shared__ int lprio[MAXL];
    __shared__ float lw[MAXL];
    __shared__ int lcnt;

    // stage src/dst (L2-hot: 64 blocks/batch reuse the same 32 KB)
    const int4* gs = (const int4*)(src + (size_t)b * SS);
    const int4* gd = (const int4*)(dst + (size_t)b * SS);
    int4* s4 = (int4*)ssrc;
    int4* d4 = (int4*)sdst;
    for (int i = tid; i < SS / 4; i += 256) { s4[i] = gs[i]; d4[i] = gd[i]; }
    for (int i = tid; i < RPB * (NN / 32); i += 256) ((unsigned*)sbits)[i] = 0u;
    if (tid == 0) lcnt = 0;
    __syncthreads();

    // scan edges for rows we own
    const float* wb = wbuf + (size_t)b * SS;
    for (int s = tid; s < SS; s += 256) {
        int sv = ssrc[s], dv = sdst[s];
        unsigned lr1 = (unsigned)(sv - r0);
        if (lr1 < RPB) {                       // pass-1 cell (sv, dv)
            int idx = atomicAdd(&lcnt, 1);
            lrc[idx] = (int)((lr1 << 16) | (unsigned)dv);
            lprio[idx] = s + 1;
            lw[idx] = wb[s];
            atomicOr(&sbits[lr1][dv >> 5], 1u << (dv & 31));
        }
        unsigned lr2 = (unsigned)(dv - r0);
        if (lr2 < RPB) {                       // pass-2 cell (dv, sv)
            int idx = atomicAdd(&lcnt, 1);
            lrc[idx] = (int)((lr2 << 16) | (unsigned)sv);
            lprio[idx] = SS + s + 1;
            lw[idx] = wb[s];
            atomicOr(&sbits[lr2][sv >> 5], 1u << (sv & 31));
        }
    }
    __syncthreads();

    int cnt = lcnt;
    // stream 16 rows: iteration lr -> row r0+lr; lane tid covers cols 4t..4t+3
    for (int lr = 0; lr < RPB; ++lr) {
        int colBase = tid << 2;
        unsigned word = sbits[lr][tid >> 3];
        unsigned bits = (word >> ((tid & 7) << 2)) & 0xFu;
        float4 v = make_float4(0.f, 0.f, 0.f, 0.f);
        if (bits) {                            // rare (~128 cells / 16K chunks)
            float* ve = &v.x;
            #pragma unroll
            for (int e = 0; e < 4; ++e) {
                if (bits & (1u << e)) {
                    int target = (lr << 16) | (colBase + e);
                    int bp = -1; float bw = 0.f;
                    for (int j = 0; j < cnt; ++j)
                        if (lrc[j] == target && lprio[j] > bp) { bp = lprio[j]; bw = lw[j]; }
                    ve[e] = bw;
                }
            }
        }
        float4* outrow = (float4*)(adj + ((size_t)b * NN + (r0 + lr)) * NN);
        outrow[tid] = v;                       // 256 lanes x 16 B = one full row
    }
}

extern "C" void kernel_launch(void* const* d_in, const int* in_sizes, int n_in,
                              void* d_out, int out_size, void* d_ws, size_t ws_size,
                              hipStream_t stream) {
    const float* flow = (const float*)d_in[0];   // (B,S,64)
    const int*   src  = (const int*)d_in[1];     // (B,S)
    const int*   dst  = (const int*)d_in[2];     // (B,S)
    const float* vol  = (const float*)d_in[3];   // (B,S)
    const float* emb  = (const float*)d_in[4];   // (1024,64)
    const float* W1   = (const float*)d_in[5];   // (128,32)
    const float* b1   = (const float*)d_in[6];   // (32,)
    const float* W2   = (const float*)d_in[7];   // (32,1)
    const float* b2   = (const float*)d_in[8];   // (1,)

    float* nf  = (float*)d_out;                         // (B,N,64)
    float* adj = nf + (size_t)BB * NN * FEAT_;          // (B,N,N)
    float* wbuf = (float*)d_ws;                         // (B,S) edge weights

    // Every output byte is written exactly once by the kernels below —
    // no memset of d_out at all.
    mlp_kernel<<<(BB * SS) / 256, 256, 0, stream>>>(src, dst, vol, emb,
                                                    W1, b1, W2, b2, wbuf);
    adj_row_kernel<<<BB * (NN / RPB), 256, 0, stream>>>(src, dst, wbuf, adj);
    node_feat_kernel<<<(BB * NN) / 4, 256, 0, stream>>>(flow, dst, nf);
}

// Round 4
// 274.886 us; speedup vs baseline: 3.6585x; 3.6585x over previous
//
#include <hip/hip_runtime.h>
#include <cstdint>
#include <cstddef>

// Problem constants (match reference setup_inputs)
#define BB 32
#define SS 4096          // 2^12
#define FEAT_ 64
#define HID_ 32
#define NN 1024          // MAX_NODES
#define RPB 8            // adjacency rows per block (dense LDS tile = 32 KB)

// ---------------------------------------------------------------------------
// Kernel 1: node_features via GATHER (no atomics) + fused L2-normalize.
// One block = 256 threads = 4 waves = 4 node rows of one batch.
// Block stages dst[b, 0..S) in LDS (16 KB); each wave scans it in 64
// ballot-iterations. Row sum accumulated in-register (deterministic s-order),
// L2-normalized via 64-lane butterfly, written out directly.
// ---------------------------------------------------------------------------
__global__ void node_feat_kernel(const float* __restrict__ flow,
                                 const int* __restrict__ dst,
                                 float* __restrict__ nf) {
    int row0 = blockIdx.x << 2;              // global row = b*NN + node
    int b = row0 >> 10;
    __shared__ int sdst[SS];

    const int4* g = (const int4*)(dst + (size_t)b * SS);
    int4* sd4 = (int4*)sdst;
    for (int i = threadIdx.x; i < SS / 4; i += 256) sd4[i] = g[i];
    __syncthreads();

    int wave = threadIdx.x >> 6;
    int lane = threadIdx.x & 63;
    int node = (row0 + wave) & (NN - 1);
    const float* fb = flow + ((size_t)b * SS << 6);

    float acc = 0.0f;
    for (int s0 = 0; s0 < SS; s0 += 64) {
        int d = sdst[s0 + lane];
        unsigned long long m = __ballot(d == node);
        while (m) {
            int bit = __ffsll((long long)m) - 1;
            m &= m - 1;
            acc += fb[((s0 + bit) << 6) + lane];   // coalesced 256 B row read
        }
    }

    float ss = acc * acc;
    #pragma unroll
    for (int off = 32; off > 0; off >>= 1) ss += __shfl_xor(ss, off, 64);
    float denom = fmaxf(sqrtf(ss), 1e-12f);
    nf[((size_t)(row0 + wave) << 6) + lane] = acc / denom;
}

// ---------------------------------------------------------------------------
// Kernel 2: edge MLP -> weight w[b,s] into workspace. No adjacency access.
// ---------------------------------------------------------------------------
__global__ void mlp_kernel(const int* __restrict__ src,
                           const int* __restrict__ dst,
                           const float* __restrict__ vol,
                           const float* __restrict__ emb,
                           const float* __restrict__ W1,
                           const float* __restrict__ b1,
                           const float* __restrict__ W2,
                           const float* __restrict__ b2,
                           float* __restrict__ wout) {
    int i = blockIdx.x * blockDim.x + threadIdx.x;  // b*S + s
    int si = src[i], di = dst[i];

    float acc[HID_];
    #pragma unroll
    for (int j = 0; j < HID_; ++j) acc[j] = b1[j];

    // h = relu([emb[src]; emb[dst]] @ W1 + b1). W1 accesses are wave-uniform
    // (scalar-load friendly); emb rows are gathered, 256 B each, L2-resident.
    #pragma unroll
    for (int half = 0; half < 2; ++half) {
        const float* e = emb + ((half ? di : si) << 6);
        const float* w = W1 + half * 64 * HID_;
        for (int k = 0; k < 64; k += 4) {
            float4 v = *(const float4*)(e + k);
            #pragma unroll
            for (int j = 0; j < HID_; ++j) {
                float a = acc[j];
                a += v.x * w[(k + 0) * HID_ + j];
                a += v.y * w[(k + 1) * HID_ + j];
                a += v.z * w[(k + 2) * HID_ + j];
                a += v.w * w[(k + 3) * HID_ + j];
                acc[j] = a;
            }
        }
    }

    float dotv = b2[0];
    #pragma unroll
    for (int j = 0; j < HID_; ++j) dotv += fmaxf(acc[j], 0.0f) * W2[j];
    float edge_w = 1.0f / (1.0f + expf(-dotv));
    float vol_w  = 1.0f / (1.0f + expf(-vol[i] / 1000.0f));
    wout[i] = edge_w * vol_w;
}

// ---------------------------------------------------------------------------
// Kernel 3: adjacency via dense LDS priority tile. Block owns RPB=8 rows of
// one batch: D[8][1024] ints (32 KB).
//   phase 0: zero D (untouched cells -> 0.0f for free)
//   phase 1: matched edges atomicMax prio into D
//            prio = s+1 (pass-1 cell src,dst) / S+s+1 (pass-2 cell dst,src)
//            ranges disjoint & unique -> max == numpy last-write-wins
//   phase 2: the unique max-prio winner per cell replaces prio with w bits
//            (w in (0,1): bit pattern < 0x3F800000 but always > 8192* — and
//             losers compare against their own prio, which can't match either)
//   phase 3: stream D out as coalesced float4 rows — every adjacency byte
//            written exactly once, no memset, no global atomics, O(1) lookups.
// src/dst are read twice from global instead of staged: 32 KB/batch stays
// L2-hot across the 128 blocks of that batch.
// ---------------------------------------------------------------------------
__global__ void adj_dense_kernel(const int* __restrict__ src,
                                 const int* __restrict__ dst,
                                 const float* __restrict__ wbuf,
                                 float* __restrict__ adj) {
    int b  = blockIdx.x >> 7;                 // 128 blocks per batch
    int r0 = (blockIdx.x & 127) << 3;         // first of RPB rows
    int tid = threadIdx.x;

    __shared__ int D[RPB * NN];               // 32 KB dense tile

    int4* D4 = (int4*)D;
    int4 z; z.x = z.y = z.z = z.w = 0;
    #pragma unroll
    for (int i = 0; i < RPB * NN / 4 / 256; ++i) D4[tid + i * 256] = z;
    __syncthreads();

    const int* sb = src + (size_t)b * SS;
    const int* db = dst + (size_t)b * SS;

    // phase 1: priority max
    for (int s = tid; s < SS; s += 256) {
        int sv = sb[s], dv = db[s];
        unsigned lr1 = (unsigned)(sv - r0);
        if (lr1 < RPB) atomicMax(&D[(lr1 << 10) + dv], s + 1);
        unsigned lr2 = (unsigned)(dv - r0);
        if (lr2 < RPB) atomicMax(&D[(lr2 << 10) + sv], SS + s + 1);
    }
    __syncthreads();

    // phase 2: winners deposit w
    const float* wb = wbuf + (size_t)b * SS;
    for (int s = tid; s < SS; s += 256) {
        int sv = sb[s], dv = db[s];
        unsigned lr1 = (unsigned)(sv - r0);
        unsigned lr2 = (unsigned)(dv - r0);
        if ((lr1 < RPB) | (lr2 < RPB)) {
            int wbits = __float_as_int(wb[s]);
            if (lr1 < RPB && D[(lr1 << 10) + dv] == s + 1)
                D[(lr1 << 10) + dv] = wbits;
            if (lr2 < RPB && D[(lr2 << 10) + sv] == SS + s + 1)
                D[(lr2 << 10) + sv] = wbits;
        }
    }
    __syncthreads();

    // phase 3: stream 8 full rows (32 KB contiguous) out, coalesced float4
    const float4* Df = (const float4*)D;
    float4* out = (float4*)(adj + ((size_t)b * NN + r0) * NN);
    #pragma unroll
    for (int i = 0; i < RPB * NN / 4 / 256; ++i) out[tid + i * 256] = Df[tid + i * 256];
}

extern "C" void kernel_launch(void* const* d_in, const int* in_sizes, int n_in,
                              void* d_out, int out_size, void* d_ws, size_t ws_size,
                              hipStream_t stream) {
    const float* flow = (const float*)d_in[0];   // (B,S,64)
    const int*   src  = (const int*)d_in[1];     // (B,S)
    const int*   dst  = (const int*)d_in[2];     // (B,S)
    const float* vol  = (const float*)d_in[3];   // (B,S)
    const float* emb  = (const float*)d_in[4];   // (1024,64)
    const float* W1   = (const float*)d_in[5];   // (128,32)
    const float* b1   = (const float*)d_in[6];   // (32,)
    const float* W2   = (const float*)d_in[7];   // (32,1)
    const float* b2   = (const float*)d_in[8];   // (1,)

    float* nf  = (float*)d_out;                         // (B,N,64)
    float* adj = nf + (size_t)BB * NN * FEAT_;          // (B,N,N)
    float* wbuf = (float*)d_ws;                         // (B,S) edge weights

    // Every output byte is written exactly once by the kernels below —
    // no memset of d_out at all.
    mlp_kernel<<<(BB * SS) / 256, 256, 0, stream>>>(src, dst, vol, emb,
                                                    W1, b1, W2, b2, wbuf);
    adj_dense_kernel<<<BB * (NN / RPB), 256, 0, stream>>>(src, dst, wbuf, adj);
    node_feat_kernel<<<(BB * NN) / 4, 256, 0, stream>>>(flow, dst, nf);
}

// Round 5
// 242.008 us; speedup vs baseline: 4.1556x; 1.1359x over previous
//
#include <hip/hip_runtime.h>
#include <cstdint>
#include <cstddef>

// Problem constants (match reference setup_inputs)
#define BB 32
#define SS 4096          // 2^12
#define FEAT_ 64
#define HID_ 32
#define NN 1024          // MAX_NODES
#define RPB 8            // adjacency rows per block (dense LDS tile = 32 KB)

typedef int v4i __attribute__((ext_vector_type(4)));

// ---------------------------------------------------------------------------
// Kernel 1: node_features via GATHER (no atomics) + fused L2-normalize.
// Block = 256 threads = 4 waves; block owns 16 rows (4 per wave) of one
// batch, amortizing one 16 KB dst staging over 16 rows (staging traffic
// 134->33.5 MB) and cutting ballot-scan wave-iterations 4x vs round 4.
// Row sums accumulate in-register in s-order (deterministic), butterfly
// L2-normalize, non-temporal row writes.
// ---------------------------------------------------------------------------
__global__ void node_feat_kernel(const float* __restrict__ flow,
                                 const int* __restrict__ dst,
                                 float* __restrict__ nf) {
    int row0 = blockIdx.x << 4;              // global row = b*NN + node
    int b = row0 >> 10;
    __shared__ int sdst[SS];

    const int4* g = (const int4*)(dst + (size_t)b * SS);
    int4* sd4 = (int4*)sdst;
    for (int i = threadIdx.x; i < SS / 4; i += 256) sd4[i] = g[i];
    __syncthreads();

    int wave = threadIdx.x >> 6;
    int lane = threadIdx.x & 63;
    int r0 = row0 + (wave << 2);             // this wave's first row
    int node0 = r0 & (NN - 1);
    const float* fb = flow + ((size_t)b * SS << 6);

    float acc[4] = {0.f, 0.f, 0.f, 0.f};
    for (int s0 = 0; s0 < SS; s0 += 64) {
        int d = sdst[s0 + lane];
        #pragma unroll
        for (int j = 0; j < 4; ++j) {
            unsigned long long m = __ballot(d == node0 + j);
            while (m) {                      // ~1 hit per wave per j over whole scan
                int bit = __ffsll((long long)m) - 1;
                m &= m - 1;
                acc[j] += fb[((s0 + bit) << 6) + lane];  // coalesced 256 B row
            }
        }
    }

    #pragma unroll
    for (int j = 0; j < 4; ++j) {
        float ss = acc[j] * acc[j];
        #pragma unroll
        for (int off = 32; off > 0; off >>= 1) ss += __shfl_xor(ss, off, 64);
        float v = acc[j] / fmaxf(sqrtf(ss), 1e-12f);
        __builtin_nontemporal_store(v, &nf[((size_t)(r0 + j) << 6) + lane]);
    }
}

// ---------------------------------------------------------------------------
// Kernel 2: edge MLP -> weight w[b,s] into workspace. No adjacency access.
// ---------------------------------------------------------------------------
__global__ void mlp_kernel(const int* __restrict__ src,
                           const int* __restrict__ dst,
                           const float* __restrict__ vol,
                           const float* __restrict__ emb,
                           const float* __restrict__ W1,
                           const float* __restrict__ b1,
                           const float* __restrict__ W2,
                           const float* __restrict__ b2,
                           float* __restrict__ wout) {
    int i = blockIdx.x * blockDim.x + threadIdx.x;  // b*S + s
    int si = src[i], di = dst[i];

    float acc[HID_];
    #pragma unroll
    for (int j = 0; j < HID_; ++j) acc[j] = b1[j];

    // h = relu([emb[src]; emb[dst]] @ W1 + b1). W1 accesses are wave-uniform
    // (scalar-load friendly); emb rows are gathered, 256 B each, L2-resident.
    #pragma unroll
    for (int half = 0; half < 2; ++half) {
        const float* e = emb + ((half ? di : si) << 6);
        const float* w = W1 + half * 64 * HID_;
        for (int k = 0; k < 64; k += 4) {
            float4 v = *(const float4*)(e + k);
            #pragma unroll
            for (int j = 0; j < HID_; ++j) {
                float a = acc[j];
                a += v.x * w[(k + 0) * HID_ + j];
                a += v.y * w[(k + 1) * HID_ + j];
                a += v.z * w[(k + 2) * HID_ + j];
                a += v.w * w[(k + 3) * HID_ + j];
                acc[j] = a;
            }
        }
    }

    float dotv = b2[0];
    #pragma unroll
    for (int j = 0; j < HID_; ++j) dotv += fmaxf(acc[j], 0.0f) * W2[j];
    float edge_w = 1.0f / (1.0f + expf(-dotv));
    float vol_w  = 1.0f / (1.0f + expf(-vol[i] / 1000.0f));
    wout[i] = edge_w * vol_w;
}

// ---------------------------------------------------------------------------
// Kernel 3: adjacency via dense LDS priority tile. Block owns RPB=8 rows of
// one batch: D[8][1024] ints (32 KB).
//   phase 0: zero D (untouched cells -> 0.0f for free)
//   phase 1: matched edges atomicMax prio into D
//            prio = s+1 (pass-1 cell src,dst) / S+s+1 (pass-2 cell dst,src)
//            ranges disjoint & unique -> max == numpy last-write-wins
//   phase 2: the unique max-prio winner per cell replaces prio with w bits
//   phase 3: stream D out as NON-TEMPORAL float4 stores (bypass L2
//            write-allocate: 134 MB through a 32 MB L2 was thrashing).
// src/dst values are register-cached across phases (16 pairs/thread), so
// global edge reads happen exactly once per block.
// ---------------------------------------------------------------------------
__global__ void adj_dense_kernel(const int* __restrict__ src,
                                 const int* __restrict__ dst,
                                 const float* __restrict__ wbuf,
                                 float* __restrict__ adj) {
    int b  = blockIdx.x >> 7;                 // 128 blocks per batch
    int r0 = (blockIdx.x & 127) << 3;         // first of RPB rows
    int tid = threadIdx.x;

    __shared__ int D[RPB * NN];               // 32 KB dense tile

    // register-cache this thread's 16 edge (src,dst) pairs while zeroing D
    const int* sb = src + (size_t)b * SS;
    const int* db = dst + (size_t)b * SS;
    int svr[16], dvr[16];
    #pragma unroll
    for (int i = 0; i < 16; ++i) {
        svr[i] = sb[tid + (i << 8)];
        dvr[i] = db[tid + (i << 8)];
    }

    int4* D4 = (int4*)D;
    int4 z; z.x = z.y = z.z = z.w = 0;
    #pragma unroll
    for (int i = 0; i < RPB * NN / 4 / 256; ++i) D4[tid + i * 256] = z;
    __syncthreads();

    // phase 1: priority max
    #pragma unroll
    for (int i = 0; i < 16; ++i) {
        int s = tid + (i << 8);
        unsigned lr1 = (unsigned)(svr[i] - r0);
        if (lr1 < RPB) atomicMax(&D[(lr1 << 10) + dvr[i]], s + 1);
        unsigned lr2 = (unsigned)(dvr[i] - r0);
        if (lr2 < RPB) atomicMax(&D[(lr2 << 10) + svr[i]], SS + s + 1);
    }
    __syncthreads();

    // phase 2: winners deposit w
    const float* wb = wbuf + (size_t)b * SS;
    #pragma unroll
    for (int i = 0; i < 16; ++i) {
        int s = tid + (i << 8);
        unsigned lr1 = (unsigned)(svr[i] - r0);
        unsigned lr2 = (unsigned)(dvr[i] - r0);
        if ((lr1 < RPB) | (lr2 < RPB)) {
            int wbits = __float_as_int(wb[s]);
            if (lr1 < RPB && D[(lr1 << 10) + dvr[i]] == s + 1)
                D[(lr1 << 10) + dvr[i]] = wbits;
            if (lr2 < RPB && D[(lr2 << 10) + svr[i]] == SS + s + 1)
                D[(lr2 << 10) + svr[i]] = wbits;
        }
    }
    __syncthreads();

    // phase 3: stream 8 full rows (32 KB contiguous) out, nt float4 stores
    const v4i* Df = (const v4i*)D;
    v4i* out = (v4i*)(adj + ((size_t)b * NN + r0) * NN);
    #pragma unroll
    for (int i = 0; i < RPB * NN / 4 / 256; ++i)
        __builtin_nontemporal_store(Df[tid + i * 256], &out[tid + i * 256]);
}

extern "C" void kernel_launch(void* const* d_in, const int* in_sizes, int n_in,
                              void* d_out, int out_size, void* d_ws, size_t ws_size,
                              hipStream_t stream) {
    const float* flow = (const float*)d_in[0];   // (B,S,64)
    const int*   src  = (const int*)d_in[1];     // (B,S)
    const int*   dst  = (const int*)d_in[2];     // (B,S)
    const float* vol  = (const float*)d_in[3];   // (B,S)
    const float* emb  = (const float*)d_in[4];   // (1024,64)
    const float* W1   = (const float*)d_in[5];   // (128,32)
    const float* b1   = (const float*)d_in[6];   // (32,)
    const float* W2   = (const float*)d_in[7];   // (32,1)
    const float* b2   = (const float*)d_in[8];   // (1,)

    float* nf  = (float*)d_out;                         // (B,N,64)
    float* adj = nf + (size_t)BB * NN * FEAT_;          // (B,N,N)
    float* wbuf = (float*)d_ws;                         // (B,S) edge weights

    // Every output byte is written exactly once by the kernels below —
    // no memset of d_out at all.
    mlp_kernel<<<(BB * SS) / 256, 256, 0, stream>>>(src, dst, vol, emb,
                                                    W1, b1, W2, b2, wbuf);
    adj_dense_kernel<<<BB * (NN / RPB), 256, 0, stream>>>(src, dst, wbuf, adj);
    node_feat_kernel<<<(BB * NN) / 16, 256, 0, stream>>>(flow, dst, nf);
}